// Round 1
// baseline (4922.049 us; speedup 1.0000x reference)
//
#include <hip/hip_runtime.h>

#define TT 4000   // timesteps
#define HH 64     // hidden
#define NB 256    // batch
#define EE 128    // fc out

// Fast activations: v_exp_f32 + v_rcp_f32. ~1 ulp, fine vs 3.4e-3 absmax threshold.
__device__ __forceinline__ float fsig(float x) {
    return __builtin_amdgcn_rcpf(1.f + __expf(-x));
}
__device__ __forceinline__ float ftanh(float x) {
    return fmaf(2.f, __builtin_amdgcn_rcpf(1.f + __expf(-2.f * x)), -1.f);
}

// One block per batch element. Thread g owns gate row g (i:0-63, f:64-127,
// g:128-191, o:192-255 — PyTorch order) for BOTH layers; weight rows live in
// VGPRs (3*64 floats; launch_bounds(256,1) -> up to 512 VGPR budget, no spill).
__global__ __launch_bounds__(256, 1)
void lstm2_fc_kernel(const float* __restrict__ x,      // [B, T, 1]
                     const float* __restrict__ W_ih0,  // [256, 1]
                     const float* __restrict__ W_hh0,  // [256, 64]
                     const float* __restrict__ b_ih0,  // [256]
                     const float* __restrict__ b_hh0,  // [256]
                     const float* __restrict__ W_ih1,  // [256, 64]
                     const float* __restrict__ W_hh1,  // [256, 64]
                     const float* __restrict__ b_ih1,  // [256]
                     const float* __restrict__ b_hh1,  // [256]
                     const float* __restrict__ W_fc,   // [128, 64]
                     const float* __restrict__ b_fc,   // [128]
                     float* __restrict__ out)          // [B, 128]
{
    const int b = blockIdx.x;
    const int g = threadIdx.x;   // 0..255

    __shared__ float x_s[TT];        // whole input sequence for this batch (16 KB)
    __shared__ float h0_s[HH];
    __shared__ float h1_s[HH];
    __shared__ float gates_s[4 * HH];

    // Preload x[b, :] into LDS (coalesced).
    for (int t = g; t < TT; t += 256) x_s[t] = x[(size_t)b * TT + t];

    // Load this thread's weight rows into registers (float4 vectorized).
    float w_hh0[HH], w_ih1[HH], w_hh1[HH];
    {
        const float4* p0 = (const float4*)(W_hh0 + g * HH);
        const float4* p1 = (const float4*)(W_ih1 + g * HH);
        const float4* p2 = (const float4*)(W_hh1 + g * HH);
        #pragma unroll
        for (int k = 0; k < HH / 4; ++k) {
            float4 v0 = p0[k], v1 = p1[k], v2 = p2[k];
            w_hh0[4*k+0] = v0.x; w_hh0[4*k+1] = v0.y; w_hh0[4*k+2] = v0.z; w_hh0[4*k+3] = v0.w;
            w_ih1[4*k+0] = v1.x; w_ih1[4*k+1] = v1.y; w_ih1[4*k+2] = v1.z; w_ih1[4*k+3] = v1.w;
            w_hh1[4*k+0] = v2.x; w_hh1[4*k+1] = v2.y; w_hh1[4*k+2] = v2.z; w_hh1[4*k+3] = v2.w;
        }
    }
    const float wx  = W_ih0[g];               // C_in == 1
    const float bb0 = b_ih0[g] + b_hh0[g];
    const float bb1 = b_ih1[g] + b_hh1[g];
    const int gate_type = g >> 6;             // 0:i 1:f 2:g 3:o (wave-uniform)

    float c0 = 0.f, c1 = 0.f;
    if (g < HH) { h0_s[g] = 0.f; h1_s[g] = 0.f; }
    __syncthreads();

    for (int t = 0; t < TT; ++t) {
        // Layer-1 partial with OLD h1 (independent of this step's layer 0).
        float acc1 = bb1;
        #pragma unroll
        for (int k = 0; k < HH; ++k) acc1 = fmaf(w_hh1[k], h1_s[k], acc1);

        // Layer-0 gates.
        float acc0 = fmaf(x_s[t], wx, bb0);
        #pragma unroll
        for (int k = 0; k < HH; ++k) acc0 = fmaf(w_hh0[k], h0_s[k], acc0);
        float a0 = (gate_type == 2) ? ftanh(acc0) : fsig(acc0);
        // Safe to write: wave0's reads of previous L1 gates were before last barrier.
        gates_s[g] = a0;
        __syncthreads();                       // B1: L0 gates visible

        if (g < HH) {                          // wave 0: cell update layer 0
            float iv = gates_s[g];
            float fv = gates_s[HH + g];
            float gv = gates_s[2 * HH + g];
            float ov = gates_s[3 * HH + g];
            c0 = fmaf(fv, c0, iv * gv);
            h0_s[g] = ov * ftanh(c0);
        }
        __syncthreads();                       // B2: new h0 visible

        // Layer-1: add input contribution from new h0.
        #pragma unroll
        for (int k = 0; k < HH; ++k) acc1 = fmaf(w_ih1[k], h0_s[k], acc1);
        float a1 = (gate_type == 2) ? ftanh(acc1) : fsig(acc1);
        gates_s[g] = a1;                       // wave0 read old gates before B2
        __syncthreads();                       // B3: L1 gates visible

        if (g < HH) {                          // wave 0: cell update layer 1
            float iv = gates_s[g];
            float fv = gates_s[HH + g];
            float gv = gates_s[2 * HH + g];
            float ov = gates_s[3 * HH + g];
            c1 = fmaf(fv, c1, iv * gv);
            h1_s[g] = ov * ftanh(c1);
        }
        __syncthreads();                       // B4: new h1 visible
    }

    // FC on final h1: out[b, e] = W_fc[e,:] . h1 + b_fc[e]
    if (g < EE) {
        float acc = b_fc[g];
        const float4* wf = (const float4*)(W_fc + g * HH);
        #pragma unroll
        for (int k = 0; k < HH / 4; ++k) {
            float4 v = wf[k];
            acc = fmaf(v.x, h1_s[4*k+0], acc);
            acc = fmaf(v.y, h1_s[4*k+1], acc);
            acc = fmaf(v.z, h1_s[4*k+2], acc);
            acc = fmaf(v.w, h1_s[4*k+3], acc);
        }
        out[(size_t)b * EE + g] = acc;
    }
}

extern "C" void kernel_launch(void* const* d_in, const int* in_sizes, int n_in,
                              void* d_out, int out_size, void* d_ws, size_t ws_size,
                              hipStream_t stream) {
    const float* x     = (const float*)d_in[0];
    const float* W_ih0 = (const float*)d_in[1];
    const float* W_hh0 = (const float*)d_in[2];
    const float* b_ih0 = (const float*)d_in[3];
    const float* b_hh0 = (const float*)d_in[4];
    const float* W_ih1 = (const float*)d_in[5];
    const float* W_hh1 = (const float*)d_in[6];
    const float* b_ih1 = (const float*)d_in[7];
    const float* b_hh1 = (const float*)d_in[8];
    const float* W_fc  = (const float*)d_in[9];
    const float* b_fc  = (const float*)d_in[10];
    float* out = (float*)d_out;

    lstm2_fc_kernel<<<dim3(NB), dim3(256), 0, stream>>>(
        x, W_ih0, W_hh0, b_ih0, b_hh0, W_ih1, W_hh1, b_ih1, b_hh1, W_fc, b_fc, out);
}

// Round 2
// 4052.958 us; speedup vs baseline: 1.2144x; 1.2144x over previous
//
#include <hip/hip_runtime.h>

#define TT 4000   // timesteps
#define HH 64     // hidden
#define NB 256    // batch
#define EE 128    // fc out
#define KH 32     // per-thread reduction half

// Fast activations: v_exp_f32 + v_rcp_f32. ~1e-6 rel err, fine vs 3.4e-3 threshold.
__device__ __forceinline__ float fsig(float x) {
    return __builtin_amdgcn_rcpf(1.f + __expf(-x));
}
__device__ __forceinline__ float ftanh(float x) {
    return fmaf(2.f, __builtin_amdgcn_rcpf(1.f + __expf(-2.f * x)), -1.f);
}

// One block per batch element, 512 threads. Threads 2r and 2r+1 own gate row r
// (PyTorch order i,f,g,o over r=0..255) split along k: half 0 -> k in [0,32),
// half 1 -> [32,64). 3x32=96 weight floats per thread stay in VGPRs (no spill;
// R1's 192-float variant spilled at VGPR_Count=144). Half-sums combine via
// __shfl_xor(acc,1) within the lane pair.
__global__ __launch_bounds__(512, 2)
void lstm2_fc_kernel(const float* __restrict__ x,      // [B, T, 1]
                     const float* __restrict__ W_ih0,  // [256, 1]
                     const float* __restrict__ W_hh0,  // [256, 64]
                     const float* __restrict__ b_ih0,  // [256]
                     const float* __restrict__ b_hh0,  // [256]
                     const float* __restrict__ W_ih1,  // [256, 64]
                     const float* __restrict__ W_hh1,  // [256, 64]
                     const float* __restrict__ b_ih1,  // [256]
                     const float* __restrict__ b_hh1,  // [256]
                     const float* __restrict__ W_fc,   // [128, 64]
                     const float* __restrict__ b_fc,   // [128]
                     float* __restrict__ out)          // [B, 128]
{
    const int b    = blockIdx.x;
    const int tid  = threadIdx.x;   // 0..511
    const int r    = tid >> 1;      // gate row 0..255
    const int half = tid & 1;       // which k-half
    const int k0   = half * KH;

    __shared__ float x_s[TT];       // 16 KB: whole input sequence for this batch
    __shared__ float h0_s[HH];
    __shared__ float h1_s[HH];
    __shared__ float gates_s[4 * HH];

    // Preload x[b, :] (coalesced).
    for (int t = tid; t < TT; t += 512) x_s[t] = x[(size_t)b * TT + t];

    // This thread's 3 half-rows of weights -> VGPRs (float4 loads).
    float w_hh0[KH], w_ih1[KH], w_hh1[KH];
    {
        const float4* p0 = (const float4*)(W_hh0 + r * HH + k0);
        const float4* p1 = (const float4*)(W_ih1 + r * HH + k0);
        const float4* p2 = (const float4*)(W_hh1 + r * HH + k0);
        #pragma unroll
        for (int k = 0; k < KH / 4; ++k) {
            float4 v0 = p0[k], v1 = p1[k], v2 = p2[k];
            w_hh0[4*k+0] = v0.x; w_hh0[4*k+1] = v0.y; w_hh0[4*k+2] = v0.z; w_hh0[4*k+3] = v0.w;
            w_ih1[4*k+0] = v1.x; w_ih1[4*k+1] = v1.y; w_ih1[4*k+2] = v1.z; w_ih1[4*k+3] = v1.w;
            w_hh1[4*k+0] = v2.x; w_hh1[4*k+1] = v2.y; w_hh1[4*k+2] = v2.z; w_hh1[4*k+3] = v2.w;
        }
    }
    const float wx  = W_ih0[r];                       // C_in == 1
    const float bb0 = b_ih0[r] + b_hh0[r];
    const float bb1 = b_ih1[r] + b_hh1[r];
    const int gate_type = r >> 6;                     // wave-uniform (32 rows/wave)

    float c0 = 0.f, c1 = 0.f;                         // c0 live in wave0, c1 in wave1
    if (tid < HH) { h0_s[tid] = 0.f; h1_s[tid] = 0.f; }
    __syncthreads();

    for (int t = 0; t < TT; ++t) {
        // L1 recurrent partial with OLD h1 (hoisted; independent of L0 this step).
        float acc1 = half ? 0.f : bb1;
        #pragma unroll
        for (int k = 0; k < KH; ++k) acc1 = fmaf(w_hh1[k], h1_s[k0 + k], acc1);

        // L0 gates.
        float acc0 = half ? 0.f : fmaf(x_s[t], wx, bb0);
        #pragma unroll
        for (int k = 0; k < KH; ++k) acc0 = fmaf(w_hh0[k], h0_s[k0 + k], acc0);
        acc0 += __shfl_xor(acc0, 1);                  // pair-reduce (DPP)
        float a0 = (gate_type == 2) ? ftanh(acc0) : fsig(acc0);
        if (!half) gates_s[r] = a0;                   // 32 lanes -> 32 banks, conflict-free
        __syncthreads();                              // B1: L0 gates visible

        if (tid < HH) {                               // wave 0: L0 cell update
            float iv = gates_s[tid];
            float fv = gates_s[HH + tid];
            float gv = gates_s[2 * HH + tid];
            float ov = gates_s[3 * HH + tid];
            c0 = fmaf(fv, c0, iv * gv);
            h0_s[tid] = ov * ftanh(c0);
        }
        __syncthreads();                              // B2: new h0 visible

        // L1 input contribution from new h0.
        #pragma unroll
        for (int k = 0; k < KH; ++k) acc1 = fmaf(w_ih1[k], h0_s[k0 + k], acc1);
        acc1 += __shfl_xor(acc1, 1);
        float a1 = (gate_type == 2) ? ftanh(acc1) : fsig(acc1);
        if (!half) gates_s[r] = a1;
        __syncthreads();                              // B3: L1 gates visible

        if (tid >= HH && tid < 2 * HH) {              // wave 1: L1 cell update
            int j = tid - HH;
            float iv = gates_s[j];
            float fv = gates_s[HH + j];
            float gv = gates_s[2 * HH + j];
            float ov = gates_s[3 * HH + j];
            c1 = fmaf(fv, c1, iv * gv);
            h1_s[j] = ov * ftanh(c1);
        }
        __syncthreads();                              // B4: new h1 visible
    }

    // FC on final h1: out[b, e] = W_fc[e,:] . h1 + b_fc[e]
    if (tid < EE) {
        float acc = b_fc[tid];
        const float4* wf = (const float4*)(W_fc + tid * HH);
        #pragma unroll
        for (int k = 0; k < HH / 4; ++k) {
            float4 v = wf[k];
            acc = fmaf(v.x, h1_s[4*k+0], acc);
            acc = fmaf(v.y, h1_s[4*k+1], acc);
            acc = fmaf(v.z, h1_s[4*k+2], acc);
            acc = fmaf(v.w, h1_s[4*k+3], acc);
        }
        out[(size_t)b * EE + tid] = acc;
    }
}

extern "C" void kernel_launch(void* const* d_in, const int* in_sizes, int n_in,
                              void* d_out, int out_size, void* d_ws, size_t ws_size,
                              hipStream_t stream) {
    const float* x     = (const float*)d_in[0];
    const float* W_ih0 = (const float*)d_in[1];
    const float* W_hh0 = (const float*)d_in[2];
    const float* b_ih0 = (const float*)d_in[3];
    const float* b_hh0 = (const float*)d_in[4];
    const float* W_ih1 = (const float*)d_in[5];
    const float* W_hh1 = (const float*)d_in[6];
    const float* b_ih1 = (const float*)d_in[7];
    const float* b_hh1 = (const float*)d_in[8];
    const float* W_fc  = (const float*)d_in[9];
    const float* b_fc  = (const float*)d_in[10];
    float* out = (float*)d_out;

    lstm2_fc_kernel<<<dim3(NB), dim3(512), 0, stream>>>(
        x, W_ih0, W_hh0, b_ih0, b_hh0, W_ih1, W_hh1, b_ih1, b_hh1, W_fc, b_fc, out);
}

// Round 3
// 2837.097 us; speedup vs baseline: 1.7349x; 1.4286x over previous
//
#include <hip/hip_runtime.h>

#define TT 4000   // timesteps
#define HH 64     // hidden
#define NB 256    // batch
#define EE 128    // fc out
#define KH 32     // per-thread reduction half

// Fast activations: v_exp_f32 + v_rcp_f32. ~1e-6 rel err vs 3.4e-3 threshold.
__device__ __forceinline__ float fsig(float x) {
    return __builtin_amdgcn_rcpf(1.f + __expf(-x));
}
__device__ __forceinline__ float ftanh(float x) {
    return fmaf(2.f, __builtin_amdgcn_rcpf(1.f + __expf(-2.f * x)), -1.f);
}

// One block (512 thr) per batch element. Threads 2r/2r+1 own gate row r
// (i,f,g,o over r=0..255) split along k (halves [0,32)/[32,64)) for all three
// recurrent matrices (96 weight floats/thread).
//
// Layer pipelining: L1 runs one step behind L0. Iteration t computes, in ONE
// phase, L0 gates(t) from h0(t-1) and L1 gates(t-1) from {h1(t-2), h0(t-1)};
// then wave0 updates c0(t) while wave1 updates c1(t-1). 2 barriers/step.
//
// amdgpu_waves_per_eu(2,2): R2 showed the allocator targets ~6 waves/EU
// (VGPR_Count=84) and spills the 96-float weight arrays, refetched every
// step. Pinning 2/EU gives a 256-VGPR budget so weights stay resident.
__global__ __launch_bounds__(512) __attribute__((amdgpu_waves_per_eu(2, 2)))
void lstm2_fc_kernel(const float* __restrict__ x,      // [B, T, 1]
                     const float* __restrict__ W_ih0,  // [256, 1]
                     const float* __restrict__ W_hh0,  // [256, 64]
                     const float* __restrict__ b_ih0,  // [256]
                     const float* __restrict__ b_hh0,  // [256]
                     const float* __restrict__ W_ih1,  // [256, 64]
                     const float* __restrict__ W_hh1,  // [256, 64]
                     const float* __restrict__ b_ih1,  // [256]
                     const float* __restrict__ b_hh1,  // [256]
                     const float* __restrict__ W_fc,   // [128, 64]
                     const float* __restrict__ b_fc,   // [128]
                     float* __restrict__ out)          // [B, 128]
{
    const int b    = blockIdx.x;
    const int tid  = threadIdx.x;   // 0..511
    const int r    = tid >> 1;      // gate row 0..255
    const int half = tid & 1;       // k-half
    const int jb   = half * (KH / 4);  // float4 base index into h vectors

    __shared__ float x_s[TT];          // 16 KB
    __shared__ float h0_s[HH];         // h0(t-1) at compute-phase start
    __shared__ float h1_s[HH];         // h1(t-2) at compute-phase start
    __shared__ float g0_s[4 * HH];     // L0 gate activations
    __shared__ float g1_s[4 * HH];     // L1 gate activations

    for (int t = tid; t < TT; t += 512) x_s[t] = x[(size_t)b * TT + t];

    // 3 half-rows of weights -> VGPRs.
    float w_hh0[KH], w_ih1[KH], w_hh1[KH];
    {
        const float4* p0 = (const float4*)(W_hh0 + r * HH + half * KH);
        const float4* p1 = (const float4*)(W_ih1 + r * HH + half * KH);
        const float4* p2 = (const float4*)(W_hh1 + r * HH + half * KH);
        #pragma unroll
        for (int k = 0; k < KH / 4; ++k) {
            float4 v0 = p0[k], v1 = p1[k], v2 = p2[k];
            w_hh0[4*k+0] = v0.x; w_hh0[4*k+1] = v0.y; w_hh0[4*k+2] = v0.z; w_hh0[4*k+3] = v0.w;
            w_ih1[4*k+0] = v1.x; w_ih1[4*k+1] = v1.y; w_ih1[4*k+2] = v1.z; w_ih1[4*k+3] = v1.w;
            w_hh1[4*k+0] = v2.x; w_hh1[4*k+1] = v2.y; w_hh1[4*k+2] = v2.z; w_hh1[4*k+3] = v2.w;
        }
    }
    const float wx  = W_ih0[r];
    const float bb0 = b_ih0[r] + b_hh0[r];
    const float bb1 = b_ih1[r] + b_hh1[r];
    const int gate_type = r >> 6;      // wave-uniform (32 rows/wave, gate blocks of 64)

    float c0 = 0.f, c1 = 0.f;          // c0 live in wave0, c1 in wave1
    if (tid < HH) { h0_s[tid] = 0.f; h1_s[tid] = 0.f; }
    __syncthreads();

    const float4* h0v = (const float4*)h0_s;
    const float4* h1v = (const float4*)h1_s;

    // TT+1 iterations: L0 active for t<TT, L1 (one step behind) for t>0.
    for (int t = 0; t <= TT; ++t) {
        const float xt = x_s[(t < TT) ? t : 0];   // broadcast; stale at t=TT (unused)

        float acc0 = half ? 0.f : fmaf(xt, wx, bb0);
        float acc1 = half ? 0.f : bb1;
        #pragma unroll
        for (int j = 0; j < KH / 4; ++j) {
            float4 h0x = h0v[jb + j];             // 2-addr broadcast b128
            float4 h1x = h1v[jb + j];
            acc0 = fmaf(w_hh0[4*j+0], h0x.x, acc0);
            acc0 = fmaf(w_hh0[4*j+1], h0x.y, acc0);
            acc0 = fmaf(w_hh0[4*j+2], h0x.z, acc0);
            acc0 = fmaf(w_hh0[4*j+3], h0x.w, acc0);
            acc1 = fmaf(w_ih1[4*j+0], h0x.x, acc1);
            acc1 = fmaf(w_ih1[4*j+1], h0x.y, acc1);
            acc1 = fmaf(w_ih1[4*j+2], h0x.z, acc1);
            acc1 = fmaf(w_ih1[4*j+3], h0x.w, acc1);
            acc1 = fmaf(w_hh1[4*j+0], h1x.x, acc1);
            acc1 = fmaf(w_hh1[4*j+1], h1x.y, acc1);
            acc1 = fmaf(w_hh1[4*j+2], h1x.z, acc1);
            acc1 = fmaf(w_hh1[4*j+3], h1x.w, acc1);
        }
        acc0 += __shfl_xor(acc0, 1);              // pair-reduce (DPP quad-perm)
        acc1 += __shfl_xor(acc1, 1);
        if (!half) {                              // 32 lanes -> 32 banks, conflict-free
            g0_s[r] = (gate_type == 2) ? ftanh(acc0) : fsig(acc0);
            g1_s[r] = (gate_type == 2) ? ftanh(acc1) : fsig(acc1);
        }
        __syncthreads();                          // B1: gates visible; h reads drained

        if (tid < HH) {                           // wave 0: L0 cell (time t)
            if (t < TT) {
                float iv = g0_s[tid];
                float fv = g0_s[HH + tid];
                float gv = g0_s[2 * HH + tid];
                float ov = g0_s[3 * HH + tid];
                c0 = fmaf(fv, c0, iv * gv);
                h0_s[tid] = ov * ftanh(c0);
            }
        } else if (tid < 2 * HH) {                // wave 1: L1 cell (time t-1)
            if (t > 0) {
                int j = tid - HH;
                float iv = g1_s[j];
                float fv = g1_s[HH + j];
                float gv = g1_s[2 * HH + j];
                float ov = g1_s[3 * HH + j];
                c1 = fmaf(fv, c1, iv * gv);
                h1_s[j] = ov * ftanh(c1);
            }
        }
        __syncthreads();                          // B2: new h0/h1 visible
    }

    // FC on final h1 = h1(TT-1): out[b, e] = W_fc[e,:] . h1 + b_fc[e]
    if (tid < EE) {
        float acc = b_fc[tid];
        const float4* wf = (const float4*)(W_fc + tid * HH);
        #pragma unroll
        for (int k = 0; k < HH / 4; ++k) {
            float4 v = wf[k];
            acc = fmaf(v.x, h1_s[4*k+0], acc);
            acc = fmaf(v.y, h1_s[4*k+1], acc);
            acc = fmaf(v.z, h1_s[4*k+2], acc);
            acc = fmaf(v.w, h1_s[4*k+3], acc);
        }
        out[(size_t)b * EE + tid] = acc;
    }
}

extern "C" void kernel_launch(void* const* d_in, const int* in_sizes, int n_in,
                              void* d_out, int out_size, void* d_ws, size_t ws_size,
                              hipStream_t stream) {
    const float* x     = (const float*)d_in[0];
    const float* W_ih0 = (const float*)d_in[1];
    const float* W_hh0 = (const float*)d_in[2];
    const float* b_ih0 = (const float*)d_in[3];
    const float* b_hh0 = (const float*)d_in[4];
    const float* W_ih1 = (const float*)d_in[5];
    const float* W_hh1 = (const float*)d_in[6];
    const float* b_ih1 = (const float*)d_in[7];
    const float* b_hh1 = (const float*)d_in[8];
    const float* W_fc  = (const float*)d_in[9];
    const float* b_fc  = (const float*)d_in[10];
    float* out = (float*)d_out;

    lstm2_fc_kernel<<<dim3(NB), dim3(512), 0, stream>>>(
        x, W_ih0, W_hh0, b_ih0, b_hh0, W_ih1, W_hh1, b_ih1, b_hh1, W_fc, b_fc, out);
}